// Round 11
// baseline (57.370 us; speedup 1.0000x reference)
//
#include <hip/hip_runtime.h>
#include <hip/hip_bf16.h>

typedef __attribute__((ext_vector_type(8))) short short8;
typedef __attribute__((ext_vector_type(4))) float f32x4;

#define DEG 5
#define FDIM 128
#define MT 32
#define NTHR 256
#define LROW 136
#define NROWS (MT * DEG)     // 160 gather rows per block
#define NINSTR (NROWS / 4)   // 40 global_load_lds per block (4 rows each)

// Exact collapse of the Shapley subset enumeration (slots symmetric, c1
// depends only on |S|):  s_i = (1 + 147/360) x_i + (-29/600) sum_j x_nbr[j]
#define CSELF 1.4083333333333334f
#define ALPHA (-0.04833333333333333f)

__device__ __forceinline__ short f2bf(float f) {
    unsigned u = __builtin_bit_cast(unsigned, f);
    unsigned r = (u + 0x7fffu + ((u >> 16) & 1u)) >> 16;
    return (short)(r & 0xffffu);
}
__device__ __forceinline__ float bf2f(short s) {
    return __builtin_bit_cast(float, (unsigned)((unsigned short)s) << 16);
}

// ---- prep: W (fp32 [128][128]) -> bf16 fragments in MFMA fragment-linear order ----
__global__ __launch_bounds__(256) void prep_w_kernel(
    const float* __restrict__ W, short* __restrict__ wswz)
{
    int t = blockIdx.x * 256 + threadIdx.x;   // 0..2047
    int frag = t >> 6;
    int lane = t & 63;
    int tt = frag >> 2;
    int kk = frag & 3;
    int lr = lane & 15;
    int lg = lane >> 4;
    const float4* wp = reinterpret_cast<const float4*>(W + (tt * 16 + lr) * FDIM + kk * 32 + lg * 8);
    float4 w0 = wp[0], w1 = wp[1];
    short8 v;
    v[0] = f2bf(w0.x); v[1] = f2bf(w0.y); v[2] = f2bf(w0.z); v[3] = f2bf(w0.w);
    v[4] = f2bf(w1.x); v[5] = f2bf(w1.y); v[6] = f2bf(w1.z); v[7] = f2bf(w1.w);
    *reinterpret_cast<short8*>(wswz + (size_t)t * 8) = v;
}

// ---- k1: xb = bf16(x), streaming convert ----
__global__ __launch_bounds__(256) void conv_xb_kernel(
    const float* __restrict__ x, short* __restrict__ xb, long total8)
{
    long t = (long)blockIdx.x * 256 + threadIdx.x;
    if (t < total8) {
        const f32x4* xp = reinterpret_cast<const f32x4*>(x + t * 8);
        f32x4 a = xp[0], b = xp[1];
        short8 v;
        v[0] = f2bf(a[0]); v[1] = f2bf(a[1]); v[2] = f2bf(a[2]); v[3] = f2bf(a[3]);
        v[4] = f2bf(b[0]); v[5] = f2bf(b[1]); v[6] = f2bf(b[2]); v[7] = f2bf(b[3]);
        *reinterpret_cast<short8*>(xb + t * 8) = v;
    }
}

// ---- main: hardware-async scattered gather via global_load_lds.
// Each of the 40 glds instructions fetches 64 lanes x 16B from per-lane
// addresses (4 gather rows), lands linearly in LDS, costs no VGPRs, and all
// 40 issue back-to-back -> full-block gather in flight before ONE drain. ----
__global__ __launch_bounds__(NTHR) void shapley_glds_kernel(
    const short* __restrict__ xb,
    const int* __restrict__ col,
    const short* __restrict__ wswz,
    float* __restrict__ out,
    int n)
{
    __shared__ short gbuf[NROWS * FDIM];   // 40960 B, rows packed 256 B
    __shared__ short sS[MT * LROW];        // 8704 B
    __shared__ int sIdx[NROWS];            // 640 B

    const int tid = threadIdx.x;
    const int base = blockIdx.x * MT;

    if (tid < NROWS) {
        int e = base * DEG + tid;
        sIdx[tid] = (e < n * DEG) ? col[e] : 0;
    }
    __syncthreads();

    const int wave = tid >> 6;
    const int lane = tid & 63;

    // ---- async gather: instr i covers rows 4i..4i+3 ----
    for (int i = wave; i < NINSTR; i += 4) {
        int r = i * 4 + (lane >> 4);
        int nbr = sIdx[r];
        const short* gp = xb + (size_t)nbr * FDIM + (lane & 15) * 8;
        __builtin_amdgcn_global_load_lds(
            (const __attribute__((address_space(1))) unsigned int*)gp,
            (__attribute__((address_space(3))) unsigned int*)&gbuf[i * 512],
            16, 0, 0);
    }
    asm volatile("s_waitcnt vmcnt(0)" ::: "memory");
    __syncthreads();

    // ---- combine: s = CSELF*self + ALPHA*sum(nbr) -> bf16 sS ----
    const int c = tid & 15;      // 16B chunk within row
    const int s = tid >> 4;      // node slot 0..15

    #pragma unroll
    for (int u = 0; u < 2; ++u) {
        int m = u * 16 + s;                  // node 0..31 within tile
        int node = base + m;
        int nc = node < n ? node : 0;
        short8 sv = *reinterpret_cast<const short8*>(xb + (size_t)nc * FDIM + c * 8);
        short8 nb0 = *reinterpret_cast<const short8*>(&gbuf[(m * DEG + 0) * FDIM + c * 8]);
        short8 nb1 = *reinterpret_cast<const short8*>(&gbuf[(m * DEG + 1) * FDIM + c * 8]);
        short8 nb2 = *reinterpret_cast<const short8*>(&gbuf[(m * DEG + 2) * FDIM + c * 8]);
        short8 nb3 = *reinterpret_cast<const short8*>(&gbuf[(m * DEG + 3) * FDIM + c * 8]);
        short8 nb4 = *reinterpret_cast<const short8*>(&gbuf[(m * DEG + 4) * FDIM + c * 8]);
        short8 v;
        #pragma unroll
        for (int k = 0; k < 8; ++k) {
            float sum = bf2f(nb0[k]) + bf2f(nb1[k]) + bf2f(nb2[k])
                      + bf2f(nb3[k]) + bf2f(nb4[k]);
            v[k] = f2bf(CSELF * bf2f(sv[k]) + ALPHA * sum);
        }
        *reinterpret_cast<short8*>(&sS[m * LROW + c * 8]) = v;
    }
    __syncthreads();

    // ---- MFMA: 4 waves cover 2x2 quadrants of (16 rows x 64 cols) ----
    const int lr = lane & 15;
    const int lg = lane >> 4;
    const int rt = wave & 1;     // row tile
    const int cg = wave >> 1;    // col group (4 tiles of 16)

    short8 af[4];
    const short* arow = &sS[(rt * 16 + lr) * LROW];
    #pragma unroll
    for (int kk = 0; kk < 4; ++kk)
        af[kk] = *reinterpret_cast<const short8*>(arow + kk * 32 + lg * 8);

    f32x4 acc[4];
    #pragma unroll
    for (int q = 0; q < 4; ++q) acc[q] = (f32x4){0.f, 0.f, 0.f, 0.f};

    #pragma unroll
    for (int q = 0; q < 4; ++q) {
        int tcol = cg * 4 + q;
        #pragma unroll
        for (int kk = 0; kk < 4; ++kk) {
            short8 bf = *reinterpret_cast<const short8*>(
                wswz + (((size_t)(tcol * 4 + kk) * 64 + lane) * 8));
            acc[q] = __builtin_amdgcn_mfma_f32_16x16x32_bf16(af[kk], bf, acc[q], 0, 0, 0);
        }
    }

    #pragma unroll
    for (int q = 0; q < 4; ++q) {
        #pragma unroll
        for (int i = 0; i < 4; ++i) {
            int orow = base + rt * 16 + lg * 4 + i;
            if (orow < n) {
                float v = acc[q][i];
                out[(size_t)orow * FDIM + (cg * 4 + q) * 16 + lr] = v > 0.f ? v : 0.f;
            }
        }
    }
}

// ---- fallback (fp32-gather fused) if d_ws too small ----
__global__ __launch_bounds__(NTHR) void shapley_fb_kernel(
    const float* __restrict__ x,
    const int* __restrict__ col,
    const short* __restrict__ wswz,
    float* __restrict__ out,
    int n)
{
    __shared__ short sS[64 * LROW];
    __shared__ int sIdx[64 * DEG];

    const int tid = threadIdx.x;
    const int base = blockIdx.x * 64;

    for (int i = tid; i < 64 * DEG; i += NTHR) {
        int e = base * DEG + i;
        sIdx[i] = (e < n * DEG) ? col[e] : 0;
    }
    __syncthreads();

    for (int t = tid; t < 64 * 16; t += NTHR) {
        int m = t >> 4;
        int c = t & 15;
        int node = base + m;
        float a0, a1, a2, a3, a4, a5, a6, a7;
        if (node < n) {
            const float4* xp = reinterpret_cast<const float4*>(x + (size_t)node * FDIM + c * 8);
            float4 s0 = xp[0], s1 = xp[1];
            a0 = CSELF * s0.x; a1 = CSELF * s0.y; a2 = CSELF * s0.z; a3 = CSELF * s0.w;
            a4 = CSELF * s1.x; a5 = CSELF * s1.y; a6 = CSELF * s1.z; a7 = CSELF * s1.w;
            #pragma unroll
            for (int j = 0; j < DEG; ++j) {
                int nb = sIdx[m * DEG + j];
                const float4* np = reinterpret_cast<const float4*>(x + (size_t)nb * FDIM + c * 8);
                float4 b0 = np[0], b1 = np[1];
                a0 += ALPHA * b0.x; a1 += ALPHA * b0.y; a2 += ALPHA * b0.z; a3 += ALPHA * b0.w;
                a4 += ALPHA * b1.x; a5 += ALPHA * b1.y; a6 += ALPHA * b1.z; a7 += ALPHA * b1.w;
            }
        } else {
            a0 = a1 = a2 = a3 = a4 = a5 = a6 = a7 = 0.f;
        }
        short8 v;
        v[0] = f2bf(a0); v[1] = f2bf(a1); v[2] = f2bf(a2); v[3] = f2bf(a3);
        v[4] = f2bf(a4); v[5] = f2bf(a5); v[6] = f2bf(a6); v[7] = f2bf(a7);
        *reinterpret_cast<short8*>(&sS[m * LROW + c * 8]) = v;
    }
    __syncthreads();

    const int wave = tid >> 6;
    const int lane = tid & 63;
    const int lr = lane & 15;
    const int lg = lane >> 4;

    short8 afrag[4];
    const short* arow = &sS[(wave * 16 + lr) * LROW];
    #pragma unroll
    for (int kk = 0; kk < 4; ++kk)
        afrag[kk] = *reinterpret_cast<const short8*>(arow + kk * 32 + lg * 8);

    f32x4 acc[8];
    #pragma unroll
    for (int t = 0; t < 8; ++t) acc[t] = (f32x4){0.f, 0.f, 0.f, 0.f};

    #pragma unroll
    for (int t = 0; t < 8; ++t) {
        #pragma unroll
        for (int kk = 0; kk < 4; ++kk) {
            short8 bfrag = *reinterpret_cast<const short8*>(
                wswz + (((size_t)(t * 4 + kk) * 64 + lane) * 8));
            acc[t] = __builtin_amdgcn_mfma_f32_16x16x32_bf16(afrag[kk], bfrag, acc[t], 0, 0, 0);
        }
    }

    #pragma unroll
    for (int t = 0; t < 8; ++t) {
        #pragma unroll
        for (int i = 0; i < 4; ++i) {
            int nrow = base + wave * 16 + lg * 4 + i;
            if (nrow < n) {
                float v = acc[t][i];
                out[(size_t)nrow * FDIM + t * 16 + lr] = v > 0.f ? v : 0.f;
            }
        }
    }
}

extern "C" void kernel_launch(void* const* d_in, const int* in_sizes, int n_in,
                              void* d_out, int out_size, void* d_ws, size_t ws_size,
                              hipStream_t stream) {
    const float* x  = (const float*)d_in[0];
    const int* ei   = (const int*)d_in[1];
    const float* W  = (const float*)d_in[2];
    float* out      = (float*)d_out;

    int n = in_sizes[0] / FDIM;                   // 100000 nodes
    const int* col = ei + (size_t)n * DEG;        // second row of edge_index

    short* wswz = (short*)d_ws;                   // 32 KB fragment buffer
    size_t xb_off = 32768;
    size_t need   = xb_off + (size_t)n * FDIM * sizeof(short);  // + 25.6 MB bf16 x

    hipLaunchKernelGGL(prep_w_kernel, dim3(8), dim3(256), 0, stream, W, wswz);

    if (ws_size >= need) {
        short* xb = (short*)((char*)d_ws + xb_off);
        long total8 = (long)n * FDIM / 8;
        int cblocks = (int)((total8 + 255) / 256);
        hipLaunchKernelGGL(conv_xb_kernel, dim3(cblocks), dim3(256), 0, stream,
                           x, xb, total8);
        int blocks = (n + MT - 1) / MT;           // 3125 blocks
        hipLaunchKernelGGL(shapley_glds_kernel, dim3(blocks), dim3(NTHR), 0, stream,
                           xb, col, wswz, out, n);
    } else {
        int blocks = (n + 63) / 64;
        hipLaunchKernelGGL(shapley_fb_kernel, dim3(blocks), dim3(NTHR), 0, stream,
                           x, col, wswz, out, n);
    }
}